// Round 2
// baseline (11864.217 us; speedup 1.0000x reference)
//
#include <hip/hip_runtime.h>
#include <hip/hip_bf16.h>
#include <math.h>

#define BB 32
#define TT 4096
#define DD 128
#define HH 4
#define dh 32
#define VV 33
#define LL 4
#define MM (BB*TT)   // 131072 rows
#define NCHUNK (MM/128)  // 1024

__device__ __forceinline__ float b2f(unsigned short u){
  union{float f; unsigned int x;} v; v.x = ((unsigned int)u)<<16; return v.f;
}
__device__ __forceinline__ unsigned short f2b(float f){
  union{float f; unsigned int x;} v; v.f=f;
  unsigned int r = v.x + 0x7fffu + ((v.x>>16)&1u);
  return (unsigned short)(r>>16);
}
__device__ __forceinline__ float blo(unsigned int u){ union{float f;unsigned int x;}v; v.x=u<<16; return v.f;}
__device__ __forceinline__ float bhi(unsigned int u){ union{float f;unsigned int x;}v; v.x=u&0xffff0000u; return v.f;}
__device__ __forceinline__ float siluf(float x){ return x/(1.0f+expf(-x)); }

// ---------------- embedding ----------------
__global__ __launch_bounds__(256) void k_embed(const int* __restrict__ x, const float* __restrict__ emb,
                                               float* __restrict__ h){
  int i = blockIdx.x*256 + threadIdx.x;     // over MM*DD
  int bt = i>>7, c = i&127;
  h[i] = emb[x[bt]*DD + c];
}

// ---------------- rms norm (f32 src -> bf16 dst), D=128, 1 wave per row ----------------
__global__ __launch_bounds__(256) void k_rms(const float* __restrict__ src, const float* __restrict__ w,
                                             unsigned short* __restrict__ dst){
  int row = blockIdx.x*4 + (threadIdx.x>>6);
  int lane = threadIdx.x&63;
  const float2 xv = *(const float2*)(src + (size_t)row*DD + lane*2);
  float ss = xv.x*xv.x + xv.y*xv.y;
  #pragma unroll
  for (int m=1;m<64;m<<=1) ss += __shfl_xor(ss,m,64);
  float sc = rsqrtf(ss*(1.0f/128.0f)+1e-5f);
  const float2 wv = *(const float2*)(w + lane*2);
  unsigned int o = ((unsigned int)f2b(xv.y*sc*wv.y)<<16) | (unsigned int)f2b(xv.x*sc*wv.x);
  *(unsigned int*)(dst + (size_t)row*DD + lane*2) = o;
}

// ---------------- generic GEMM: out[M,N] = A[M,K] @ W[N,K]^T ----------------
// A bf16, W f32 (converted to bf16 in LDS), f32 accum.
// tile 128 rows x 64 cols, block 256, per-thread 8x4. Transposed LDS layout.
template<int ACT, int OUTADD>
__global__ __launch_bounds__(256) void k_gemm(const unsigned short* __restrict__ A,
                                              const float* __restrict__ W,
                                              void* __restrict__ outp, int N, int K){
  __shared__ unsigned short As[128*136];  // As[k][r]
  __shared__ unsigned short Ws[128*72];   // Ws[k][n]
  const int tid = threadIdx.x;
  const int row0 = blockIdx.x*128, col0 = blockIdx.y*64;
  const int trow = tid>>4, tcol = tid&15;
  float acc[8][4];
  #pragma unroll
  for (int r=0;r<8;r++){
    #pragma unroll
    for (int n=0;n<4;n++) acc[r][n]=0.f;
  }

  for (int kc=0; kc<K; kc+=128){
    #pragma unroll
    for (int ii=0; ii<8; ++ii){                 // stage A tile (128x128 bf16) transposed
      int flat = tid + ii*256;                  // 0..2047 uint4's
      int r = flat>>4, v16 = flat&15;
      uint4 g = *(const uint4*)(A + (size_t)(row0+r)*K + kc + v16*8);
      int kb = v16*8;
      As[(kb+0)*136+r] = (unsigned short)(g.x&0xffffu);
      As[(kb+1)*136+r] = (unsigned short)(g.x>>16);
      As[(kb+2)*136+r] = (unsigned short)(g.y&0xffffu);
      As[(kb+3)*136+r] = (unsigned short)(g.y>>16);
      As[(kb+4)*136+r] = (unsigned short)(g.z&0xffffu);
      As[(kb+5)*136+r] = (unsigned short)(g.z>>16);
      As[(kb+6)*136+r] = (unsigned short)(g.w&0xffffu);
      As[(kb+7)*136+r] = (unsigned short)(g.w>>16);
    }
    #pragma unroll
    for (int ii=0; ii<8; ++ii){                 // stage W tile (64x128 f32 -> bf16) transposed
      int flat = tid + ii*256;                  // 0..2047 float4's
      int n = flat>>5, k4i = flat&31;
      float4 wv = *(const float4*)(W + (size_t)(col0+n)*K + kc + k4i*4);
      Ws[(k4i*4+0)*72+n] = f2b(wv.x);
      Ws[(k4i*4+1)*72+n] = f2b(wv.y);
      Ws[(k4i*4+2)*72+n] = f2b(wv.z);
      Ws[(k4i*4+3)*72+n] = f2b(wv.w);
    }
    __syncthreads();
    #pragma unroll 4
    for (int k=0;k<128;k++){
      uint4 a4 = *(const uint4*)&As[k*136 + trow*8];
      uint2 w2 = *(const uint2*)&Ws[k*72 + tcol*4];
      float av[8] = { blo(a4.x),bhi(a4.x),blo(a4.y),bhi(a4.y),
                      blo(a4.z),bhi(a4.z),blo(a4.w),bhi(a4.w) };
      float wv[4] = { blo(w2.x),bhi(w2.x),blo(w2.y),bhi(w2.y) };
      #pragma unroll
      for (int r=0;r<8;r++){
        #pragma unroll
        for (int n=0;n<4;n++) acc[r][n] += av[r]*wv[n];
      }
    }
    __syncthreads();
  }

  if (OUTADD){
    float* O = (float*)outp;
    #pragma unroll
    for (int r=0;r<8;r++){
      int row = row0 + trow*8 + r;
      float4* p = (float4*)(O + (size_t)row*N + col0 + tcol*4);
      float4 v = *p;
      v.x += acc[r][0]; v.y += acc[r][1]; v.z += acc[r][2]; v.w += acc[r][3];
      *p = v;
    }
  } else {
    unsigned short* O = (unsigned short*)outp;
    #pragma unroll
    for (int r=0;r<8;r++){
      int row = row0 + trow*8 + r;
      float v0=acc[r][0],v1=acc[r][1],v2=acc[r][2],v3=acc[r][3];
      if (ACT){ v0=siluf(v0); v1=siluf(v1); v2=siluf(v2); v3=siluf(v3); }
      uint2 o;
      o.x = ((unsigned int)f2b(v1)<<16) | (unsigned int)f2b(v0);
      o.y = ((unsigned int)f2b(v3)<<16) | (unsigned int)f2b(v2);
      *(uint2*)(O + (size_t)row*N + col0 + tcol*4) = o;
    }
  }
}

// ---------------- beta = sigmoid(hn @ bw^T), N=4 ----------------
__global__ __launch_bounds__(256) void k_beta(const unsigned short* __restrict__ hn,
                                              const float* __restrict__ bwl, float* __restrict__ beta){
  __shared__ unsigned short As[64*128];
  int tid = threadIdx.x; int row0 = blockIdx.x*64;
  #pragma unroll
  for (int ii=0;ii<4;ii++){
    int flat = tid + ii*256;   // 1024 uint4's
    int r = flat>>4, v16 = flat&15;
    *(uint4*)&As[r*128 + v16*8] = *(const uint4*)(hn + (size_t)(row0+r)*DD + v16*8);
  }
  __syncthreads();
  int r = tid>>2, n = tid&3;
  const float* wr = bwl + n*DD;
  const unsigned short* ar = &As[r*128];
  float s = 0.f;
  #pragma unroll
  for (int k=0;k<128;k+=8){
    uint4 a = *(const uint4*)(ar + k);
    float4 wa = *(const float4*)(wr + k);
    float4 wb = *(const float4*)(wr + k + 4);
    s += blo(a.x)*wa.x + bhi(a.x)*wa.y + blo(a.y)*wa.z + bhi(a.y)*wa.w;
    s += blo(a.z)*wb.x + bhi(a.z)*wb.y + blo(a.w)*wb.z + bhi(a.w)*wb.w;
  }
  beta[(size_t)(row0+r)*HH + n] = 1.0f/(1.0f+expf(-s));
}

// ---------------- halo save: rows {chunk*128-3 .. -1} of A,B,C -> halo buf ----------------
// halo layout: [chunk][tensor][3][128] bf16.  Sequence-start chunks get zeros.
__global__ __launch_bounds__(256) void k_halo(const unsigned short* __restrict__ A,
                                              const unsigned short* __restrict__ B,
                                              const unsigned short* __restrict__ C,
                                              unsigned short* __restrict__ halo){
  int i = blockIdx.x*256 + threadIdx.x;        // over NCHUNK*3*3*128 = 1,179,648
  int ch = i & 127;
  int rt = i >> 7;            // [chunk][tensor][row3]
  int r3 = rt % 3;
  int tn = (rt/3) % 3;
  int ck = rt / 9;
  unsigned short v = 0;
  if ((ck & 31) != 0){
    const unsigned short* X = (tn==0) ? A : (tn==1) ? B : C;
    v = X[((size_t)ck*128 - 3 + r3)*DD + ch];
  }
  halo[(size_t)i] = v;
}

// ---------------- in-place causal depthwise conv(4)+silu(+l2n) over one 128-row chunk ----------------
// grid (NCHUNK, 3): blockIdx.y = tensor (0=q,1=k,2=v)
__global__ __launch_bounds__(256) void k_conv_ip(
    unsigned short* __restrict__ A, unsigned short* __restrict__ B, unsigned short* __restrict__ C,
    const float* __restrict__ qcw, const float* __restrict__ qcb,
    const float* __restrict__ kcw, const float* __restrict__ kcb,
    const float* __restrict__ vcw, const float* __restrict__ vcb,
    const unsigned short* __restrict__ halo){
  __shared__ __align__(16) unsigned short Xs[131*128];
  const int tid = threadIdx.x;
  const int ck = blockIdx.x, tn = blockIdx.y;
  unsigned short* X = (tn==0) ? A : (tn==1) ? B : C;
  const float* w = (tn==0) ? qcw : (tn==1) ? kcw : vcw;
  const float* bi = (tn==0) ? qcb : (tn==1) ? kcb : vcb;

  // stage halo rows (3x128) into Xs[0..2]
  if (tid < 48){
    int lr = tid>>4, c16 = tid&15;
    *(uint4*)&Xs[lr*128 + c16*8] = *(const uint4*)&halo[((size_t)(ck*3+tn)*3 + lr)*128 + c16*8];
  }
  // stage chunk rows (128x128) into Xs[3..130]
  #pragma unroll
  for (int ii=0; ii<8; ++ii){
    int flat = tid + ii*256;        // 2048 uint4's
    int r = flat>>4, c16 = flat&15;
    *(uint4*)&Xs[(3+r)*128 + c16*8] = *(const uint4*)&X[((size_t)ck*128 + r)*DD + c16*8];
  }
  __syncthreads();

  const int rh = tid>>7, c = tid&127;
  float w0=w[c*4+0], w1=w[c*4+1], w2=w[c*4+2], w3=w[c*4+3];
  float bc = bi[c];
  #pragma unroll 2
  for (int rr=0; rr<64; ++rr){
    int row = rr*2 + rh;
    float y = bc + w0*b2f(Xs[(row+0)*128+c]) + w1*b2f(Xs[(row+1)*128+c])
                 + w2*b2f(Xs[(row+2)*128+c]) + w3*b2f(Xs[(row+3)*128+c]);
    y = siluf(y);
    if (tn < 2){
      float s = y*y;
      #pragma unroll
      for (int m=1;m<32;m<<=1) s += __shfl_xor(s,m,64);
      y *= rsqrtf(s + 1e-6f);
      if (tn==0) y *= 0.17677669529663687f;   // / sqrt(d)
    }
    X[((size_t)ck*128 + row)*DD + c] = f2b(y);
  }
}

// ---------------- sequential delta-rule scan: one wave per (b,h) ----------------
// lane: j = lane&31 (value dim), ih = lane>>5 (key-dim half). S[i][j] i in ih*16..+15.
// NOTE: o aliases q (write o[t] happens after last read of row t). No restrict on q/o.
__global__ __launch_bounds__(64) void k_scan(const unsigned short* q, const unsigned short* __restrict__ k,
                                             const unsigned short* __restrict__ v, const float* __restrict__ beta,
                                             unsigned short* o){
  int b = blockIdx.x>>2, hh = blockIdx.x&3;
  int lane = threadIdx.x;
  int j = lane&31, ih = lane>>5;
  float S[16];
  #pragma unroll
  for (int m=0;m<16;m++) S[m]=0.f;
  size_t idx0 = ((size_t)b*TT*HH + hh)*dh;     // t-stride = 128 elems
  size_t bidx0 = (size_t)b*TT*HH + hh;         // t-stride = 4

  uint2 kr[4], qr[4]; unsigned short vr; float br;
  {
    const unsigned short* kp = k + idx0 + ih*16;
    const unsigned short* qp = q + idx0 + ih*16;
    #pragma unroll
    for (int u=0;u<4;u++){ kr[u]=*(const uint2*)(kp+u*4); qr[u]=*(const uint2*)(qp+u*4); }
    vr = v[idx0 + j];
    br = beta[bidx0];
  }
  for (int t=0;t<TT;t++){
    float kf[16], qf[16];
    #pragma unroll
    for (int u=0;u<4;u++){
      kf[u*4+0]=blo(kr[u].x); kf[u*4+1]=bhi(kr[u].x); kf[u*4+2]=blo(kr[u].y); kf[u*4+3]=bhi(kr[u].y);
      qf[u*4+0]=blo(qr[u].x); qf[u*4+1]=bhi(qr[u].x); qf[u*4+2]=blo(qr[u].y); qf[u*4+3]=bhi(qr[u].y);
    }
    float vc = b2f(vr), bc = br;
    if (t+1 < TT){                       // prefetch next step's operands
      size_t idx = idx0 + (size_t)(t+1)*128;
      const unsigned short* kp = k + idx + ih*16;
      const unsigned short* qp = q + idx + ih*16;
      #pragma unroll
      for (int u=0;u<4;u++){ kr[u]=*(const uint2*)(kp+u*4); qr[u]=*(const uint2*)(qp+u*4); }
      vr = v[idx + j];
      br = beta[bidx0 + (size_t)(t+1)*HH];
    }
    // p_j = sum_i S[i][j]*k[i]
    float p0=0,p1=0,p2=0,p3=0;
    #pragma unroll
    for (int m=0;m<4;m++){
      p0 += S[m]*kf[m]; p1 += S[m+4]*kf[m+4]; p2 += S[m+8]*kf[m+8]; p3 += S[m+12]*kf[m+12];
    }
    float p = (p0+p1)+(p2+p3);
    p += __shfl_xor(p, 32, 64);
    float err = (vc - p)*bc;
    // S += k (outer) err ; o_j = sum_i S[i][j]*q[i]
    float o0=0,o1=0,o2=0,o3=0;
    #pragma unroll
    for (int m=0;m<4;m++){
      S[m]    += kf[m]*err;     o0 += S[m]*qf[m];
      S[m+4]  += kf[m+4]*err;   o1 += S[m+4]*qf[m+4];
      S[m+8]  += kf[m+8]*err;   o2 += S[m+8]*qf[m+8];
      S[m+12] += kf[m+12]*err;  o3 += S[m+12]*qf[m+12];
    }
    float oo = (o0+o1)+(o2+o3);
    oo += __shfl_xor(oo, 32, 64);
    if (ih==0) o[idx0 + (size_t)t*128 + j] = f2b(oo);
  }
}

// ---------------- o = rms(o, hnw)*silu(gate) ----------------
__global__ __launch_bounds__(256) void k_ogate(const unsigned short* __restrict__ o, const unsigned short* __restrict__ gate,
                                               const float* __restrict__ hnwl, unsigned short* __restrict__ tmp){
  int tid=threadIdx.x;
  size_t bt = (size_t)blockIdx.x*2 + (tid>>7);
  int c = tid&127;
  size_t i = bt*DD + c;
  float ov = b2f(o[i]);
  float ss = ov*ov;
  #pragma unroll
  for (int m=1;m<32;m<<=1) ss += __shfl_xor(ss,m,64);
  float r = rsqrtf(ss*(1.0f/32.0f)+1e-5f);
  float g = b2f(gate[i]);
  tmp[i] = f2b(ov*r*hnwl[c&31]*siluf(g));
}

// ---------------- final head: out[M,33] ----------------
__global__ __launch_bounds__(256) void k_head(const unsigned short* __restrict__ hf, const float* __restrict__ hw,
                                              float* __restrict__ out){
  int gid = blockIdx.x*256+threadIdx.x;
  if (gid >= MM*VV) return;
  int row = gid/VV, n = gid - row*VV;
  const unsigned short* a = hf + (size_t)row*DD;
  const float* w = hw + n*DD;
  float s=0.f;
  #pragma unroll
  for (int k2=0;k2<128;k2+=8){
    uint4 av = *(const uint4*)(a+k2);
    float4 wa = *(const float4*)(w+k2);
    float4 wb = *(const float4*)(w+k2+4);
    s += blo(av.x)*wa.x + bhi(av.x)*wa.y + blo(av.y)*wa.z + bhi(av.y)*wa.w;
    s += blo(av.z)*wb.x + bhi(av.z)*wb.y + blo(av.w)*wb.z + bhi(av.w)*wb.w;
  }
  out[gid] = s;
}

extern "C" void kernel_launch(void* const* d_in, const int* in_sizes, int n_in,
                              void* d_out, int out_size, void* d_ws, size_t ws_size,
                              hipStream_t stream){
  const int*   x   = (const int*)d_in[0];
  const float* emb = (const float*)d_in[1];
  const float* qw  = (const float*)d_in[2];
  const float* kw  = (const float*)d_in[3];
  const float* vw  = (const float*)d_in[4];
  const float* qcw = (const float*)d_in[5];
  const float* qcb = (const float*)d_in[6];
  const float* kcw = (const float*)d_in[7];
  const float* kcb = (const float*)d_in[8];
  const float* vcw = (const float*)d_in[9];
  const float* vcb = (const float*)d_in[10];
  const float* ow  = (const float*)d_in[11];
  const float* gw  = (const float*)d_in[12];
  const float* bw  = (const float*)d_in[13];
  const float* hnw = (const float*)d_in[14];
  const float* n1w = (const float*)d_in[15];
  const float* n2w = (const float*)d_in[16];
  const float* m1w = (const float*)d_in[17];
  const float* m2w = (const float*)d_in[18];
  const float* fnw = (const float*)d_in[19];
  const float* hw  = (const float*)d_in[20];

  // ws layout (196.2 MB total):
  // h (f32 64MB) | hn (bf16 32MB) | A (32MB) | B (32MB) | C (32MB) | beta (2MB) | halo (2.25MB)
  char* ws = (char*)d_ws;
  size_t off = 0;
  float* h             = (float*)(ws+off);          off += (size_t)MM*DD*4;
  unsigned short* hn   = (unsigned short*)(ws+off); off += (size_t)MM*DD*2;
  unsigned short* A    = (unsigned short*)(ws+off); off += (size_t)MM*DD*2;
  unsigned short* B    = (unsigned short*)(ws+off); off += (size_t)MM*DD*2;
  unsigned short* C    = (unsigned short*)(ws+off); off += (size_t)MM*DD*2;
  float* beta          = (float*)(ws+off);          off += (size_t)MM*HH*4;
  unsigned short* halo = (unsigned short*)(ws+off); off += (size_t)NCHUNK*9*128*2;
  unsigned short* t1   = A;   // [M,256] spans A+B (both dead at MLP time)

  k_embed<<<MM*DD/256, 256, 0, stream>>>(x, emb, h);
  for (int l=0;l<LL;l++){
    k_rms<<<MM/4,256,0,stream>>>(h, n1w + l*DD, hn);
    k_gemm<0,0><<<dim3(MM/128,2),256,0,stream>>>(hn, qw + l*DD*DD, A, 128, 128);
    k_gemm<0,0><<<dim3(MM/128,2),256,0,stream>>>(hn, kw + l*DD*DD, B, 128, 128);
    k_gemm<0,0><<<dim3(MM/128,2),256,0,stream>>>(hn, vw + l*DD*DD, C, 128, 128);
    k_beta<<<MM/64,256,0,stream>>>(hn, bw + l*HH*DD, beta);
    k_halo<<<NCHUNK*9*128/256,256,0,stream>>>(A, B, C, halo);
    k_conv_ip<<<dim3(NCHUNK,3),256,0,stream>>>(A, B, C,
                                  qcw+l*DD*4, qcb+l*DD, kcw+l*DD*4, kcb+l*DD, vcw+l*DD*4, vcb+l*DD,
                                  halo);
    k_scan<<<BB*HH,64,0,stream>>>(A, B, C, beta, A);          // o overwrites q (in-wave order safe)
    k_gemm<0,0><<<dim3(MM/128,2),256,0,stream>>>(hn, gw + l*DD*DD, C, 128, 128);  // gate -> C (v dead)
    k_ogate<<<MM/2,256,0,stream>>>(A, C, hnw+l*dh, B);        // tmp -> B
    k_gemm<0,1><<<dim3(MM/128,2),256,0,stream>>>(B, ow + l*DD*DD, h, 128, 128);
    k_rms<<<MM/4,256,0,stream>>>(h, n2w + l*DD, hn);
    k_gemm<1,0><<<dim3(MM/128,4),256,0,stream>>>(hn, m1w + l*2*DD*DD, t1, 256, 128);
    k_gemm<0,1><<<dim3(MM/128,2),256,0,stream>>>(t1, m2w + l*2*DD*DD, h, 128, 256);
  }
  k_rms<<<MM/4,256,0,stream>>>(h, fnw, hn);
  k_head<<<(MM*VV+255)/256,256,0,stream>>>(hn, hw, (float*)d_out);
}

// Round 3
// 8554.946 us; speedup vs baseline: 1.3868x; 1.3868x over previous
//
#include <hip/hip_runtime.h>
#include <hip/hip_bf16.h>
#include <math.h>

#define BB 32
#define TT 4096
#define DD 128
#define HH 4
#define dh 32
#define VV 33
#define LL 4
#define MM (BB*TT)   // 131072 rows
#define NCHUNK (MM/128)  // 1024

typedef short short8 __attribute__((ext_vector_type(8)));
typedef float f32x4 __attribute__((ext_vector_type(4)));

__device__ __forceinline__ float b2f(unsigned short u){
  union{float f; unsigned int x;} v; v.x = ((unsigned int)u)<<16; return v.f;
}
__device__ __forceinline__ unsigned short f2b(float f){
  union{float f; unsigned int x;} v; v.f=f;
  unsigned int r = v.x + 0x7fffu + ((v.x>>16)&1u);
  return (unsigned short)(r>>16);
}
__device__ __forceinline__ float blo(unsigned int u){ union{float f;unsigned int x;}v; v.x=u<<16; return v.f;}
__device__ __forceinline__ float bhi(unsigned int u){ union{float f;unsigned int x;}v; v.x=u&0xffff0000u; return v.f;}
__device__ __forceinline__ float siluf(float x){ return x/(1.0f+expf(-x)); }

// ---------------- embedding ----------------
__global__ __launch_bounds__(256) void k_embed(const int* __restrict__ x, const float* __restrict__ emb,
                                               float* __restrict__ h){
  int i = blockIdx.x*256 + threadIdx.x;     // over MM*DD
  int bt = i>>7, c = i&127;
  h[i] = emb[x[bt]*DD + c];
}

// ---------------- rms norm (f32 src -> bf16 dst), D=128, 1 wave per row ----------------
__global__ __launch_bounds__(256) void k_rms(const float* __restrict__ src, const float* __restrict__ w,
                                             unsigned short* __restrict__ dst){
  int row = blockIdx.x*4 + (threadIdx.x>>6);
  int lane = threadIdx.x&63;
  const float2 xv = *(const float2*)(src + (size_t)row*DD + lane*2);
  float ss = xv.x*xv.x + xv.y*xv.y;
  #pragma unroll
  for (int m=1;m<64;m<<=1) ss += __shfl_xor(ss,m,64);
  float sc = rsqrtf(ss*(1.0f/128.0f)+1e-5f);
  const float2 wv = *(const float2*)(w + lane*2);
  unsigned int o = ((unsigned int)f2b(xv.y*sc*wv.y)<<16) | (unsigned int)f2b(xv.x*sc*wv.x);
  *(unsigned int*)(dst + (size_t)row*DD + lane*2) = o;
}

// ---------------- MFMA GEMM: out[M,N] = A[M,K] @ W[N,K]^T ----------------
// A bf16, W f32 (bf16-converted into LDS), f32 accum via v_mfma_f32_16x16x32_bf16.
// tile 128x64, block 256 (4 waves), wave tile 64x32 (4x2 fragments).
// LDS XOR-swizzle (T2): 8-elem group g stored at g^(row&7).
template<int ACT, int OUTADD>
__global__ __launch_bounds__(256) void k_gemm(const unsigned short* __restrict__ A,
                                              const float* __restrict__ W,
                                              void* __restrict__ outp, int N, int K){
  __shared__ __align__(16) unsigned short As[128*128];  // [r][c swz] 32KB
  __shared__ __align__(16) unsigned short Ws[64*128];   // [n][c swz] 16KB
  const int tid = threadIdx.x;
  const int lane = tid & 63, wave = tid >> 6;
  const int row0 = blockIdx.x*128, col0 = blockIdx.y*64;
  const int wr0 = (wave&1)*64, wc0 = (wave>>1)*32;
  const int fr = lane & 15, fq = lane >> 4;   // fragment row/col index, k-group
  f32x4 acc[4][2];
  #pragma unroll
  for (int m=0;m<4;m++){
    #pragma unroll
    for (int n=0;n<2;n++) acc[m][n] = (f32x4){0.f,0.f,0.f,0.f};
  }

  for (int kc=0; kc<K; kc+=128){
    #pragma unroll
    for (int ii=0; ii<8; ++ii){               // stage A tile 128x128 bf16 (16B/thread)
      int flat = tid + ii*256;                // 2048 uint4's
      int r = flat>>4, g = flat&15;
      uint4 gv = *(const uint4*)(A + (size_t)(row0+r)*K + kc + g*8);
      *(uint4*)&As[r*128 + ((g^(r&7))<<3)] = gv;
    }
    #pragma unroll
    for (int ii=0; ii<8; ++ii){               // stage W tile 64x128 f32->bf16 (4 elem/thread)
      int flat = tid + ii*256;                // 2048 float4's
      int n = flat>>5, q4 = flat&31;
      float4 wv = *(const float4*)(W + (size_t)(col0+n)*K + kc + q4*4);
      uint2 pk;
      pk.x = (unsigned int)f2b(wv.x) | ((unsigned int)f2b(wv.y)<<16);
      pk.y = (unsigned int)f2b(wv.z) | ((unsigned int)f2b(wv.w)<<16);
      int dst = n*128 + ((((q4>>1)^(n&7))<<3) | ((q4&1)<<2));
      *(uint2*)&Ws[dst] = pk;
    }
    __syncthreads();
    #pragma unroll
    for (int ks=0; ks<4; ++ks){
      int gg = ks*4 + fq;
      short8 a[4], b[2];
      #pragma unroll
      for (int m=0;m<4;m++){
        int row = wr0 + m*16 + fr;
        a[m] = *(const short8*)&As[row*128 + ((gg^(row&7))<<3)];
      }
      #pragma unroll
      for (int n=0;n<2;n++){
        int col = wc0 + n*16 + fr;
        b[n] = *(const short8*)&Ws[col*128 + ((gg^(col&7))<<3)];
      }
      #pragma unroll
      for (int m=0;m<4;m++){
        #pragma unroll
        for (int n=0;n<2;n++)
          acc[m][n] = __builtin_amdgcn_mfma_f32_16x16x32_bf16(a[m], b[n], acc[m][n], 0, 0, 0);
      }
    }
    __syncthreads();
  }

  // epilogue: C/D map col=lane&15, row=(lane>>4)*4+reg
  if (OUTADD){
    float* O = (float*)outp;
    #pragma unroll
    for (int m=0;m<4;m++){
      #pragma unroll
      for (int n=0;n<2;n++){
        int ccol = col0 + wc0 + n*16 + fr;
        #pragma unroll
        for (int r=0;r<4;r++){
          int rrow = row0 + wr0 + m*16 + fq*4 + r;
          O[(size_t)rrow*N + ccol] += acc[m][n][r];
        }
      }
    }
  } else {
    unsigned short* O = (unsigned short*)outp;
    #pragma unroll
    for (int m=0;m<4;m++){
      #pragma unroll
      for (int n=0;n<2;n++){
        int ccol = col0 + wc0 + n*16 + fr;
        #pragma unroll
        for (int r=0;r<4;r++){
          int rrow = row0 + wr0 + m*16 + fq*4 + r;
          float vv = acc[m][n][r];
          if (ACT) vv = siluf(vv);
          O[(size_t)rrow*N + ccol] = f2b(vv);
        }
      }
    }
  }
}

// ---------------- beta = sigmoid(hn @ bw^T), N=4 ----------------
__global__ __launch_bounds__(256) void k_beta(const unsigned short* __restrict__ hn,
                                              const float* __restrict__ bwl, float* __restrict__ beta){
  __shared__ unsigned short As[64*128];
  int tid = threadIdx.x; int row0 = blockIdx.x*64;
  #pragma unroll
  for (int ii=0;ii<4;ii++){
    int flat = tid + ii*256;   // 1024 uint4's
    int r = flat>>4, v16 = flat&15;
    *(uint4*)&As[r*128 + v16*8] = *(const uint4*)(hn + (size_t)(row0+r)*DD + v16*8);
  }
  __syncthreads();
  int r = tid>>2, n = tid&3;
  const float* wr = bwl + n*DD;
  const unsigned short* ar = &As[r*128];
  float s = 0.f;
  #pragma unroll
  for (int k=0;k<128;k+=8){
    uint4 a = *(const uint4*)(ar + k);
    float4 wa = *(const float4*)(wr + k);
    float4 wb = *(const float4*)(wr + k + 4);
    s += blo(a.x)*wa.x + bhi(a.x)*wa.y + blo(a.y)*wa.z + bhi(a.y)*wa.w;
    s += blo(a.z)*wb.x + bhi(a.z)*wb.y + blo(a.w)*wb.z + bhi(a.w)*wb.w;
  }
  beta[(size_t)(row0+r)*HH + n] = 1.0f/(1.0f+expf(-s));
}

// ---------------- halo save: rows {chunk*128-3 .. -1} of A,B,C -> halo buf ----------------
__global__ __launch_bounds__(256) void k_halo(const unsigned short* __restrict__ A,
                                              const unsigned short* __restrict__ B,
                                              const unsigned short* __restrict__ C,
                                              unsigned short* __restrict__ halo){
  int i = blockIdx.x*256 + threadIdx.x;        // over NCHUNK*3*3*128
  int ch = i & 127;
  int rt = i >> 7;            // [chunk][tensor][row3]
  int r3 = rt % 3;
  int tn = (rt/3) % 3;
  int ck = rt / 9;
  unsigned short v = 0;
  if ((ck & 31) != 0){
    const unsigned short* X = (tn==0) ? A : (tn==1) ? B : C;
    v = X[((size_t)ck*128 - 3 + r3)*DD + ch];
  }
  halo[(size_t)i] = v;
}

// ---------------- in-place causal depthwise conv(4)+silu(+l2n) over one 128-row chunk ----------------
__global__ __launch_bounds__(256) void k_conv_ip(
    unsigned short* __restrict__ A, unsigned short* __restrict__ B, unsigned short* __restrict__ C,
    const float* __restrict__ qcw, const float* __restrict__ qcb,
    const float* __restrict__ kcw, const float* __restrict__ kcb,
    const float* __restrict__ vcw, const float* __restrict__ vcb,
    const unsigned short* __restrict__ halo){
  __shared__ __align__(16) unsigned short Xs[131*128];
  const int tid = threadIdx.x;
  const int ck = blockIdx.x, tn = blockIdx.y;
  unsigned short* X = (tn==0) ? A : (tn==1) ? B : C;
  const float* w = (tn==0) ? qcw : (tn==1) ? kcw : vcw;
  const float* bi = (tn==0) ? qcb : (tn==1) ? kcb : vcb;

  if (tid < 48){
    int lr = tid>>4, c16 = tid&15;
    *(uint4*)&Xs[lr*128 + c16*8] = *(const uint4*)&halo[((size_t)(ck*3+tn)*3 + lr)*128 + c16*8];
  }
  #pragma unroll
  for (int ii=0; ii<8; ++ii){
    int flat = tid + ii*256;        // 2048 uint4's
    int r = flat>>4, c16 = flat&15;
    *(uint4*)&Xs[(3+r)*128 + c16*8] = *(const uint4*)&X[((size_t)ck*128 + r)*DD + c16*8];
  }
  __syncthreads();

  const int rh = tid>>7, c = tid&127;
  float w0=w[c*4+0], w1=w[c*4+1], w2=w[c*4+2], w3=w[c*4+3];
  float bc = bi[c];
  #pragma unroll 2
  for (int rr=0; rr<64; ++rr){
    int row = rr*2 + rh;
    float y = bc + w0*b2f(Xs[(row+0)*128+c]) + w1*b2f(Xs[(row+1)*128+c])
                 + w2*b2f(Xs[(row+2)*128+c]) + w3*b2f(Xs[(row+3)*128+c]);
    y = siluf(y);
    if (tn < 2){
      float s = y*y;
      #pragma unroll
      for (int m=1;m<32;m<<=1) s += __shfl_xor(s,m,64);
      y *= rsqrtf(s + 1e-6f);
      if (tn==0) y *= 0.17677669529663687f;   // / sqrt(d)
    }
    X[((size_t)ck*128 + row)*DD + c] = f2b(y);
  }
}

// ---------------- sequential delta-rule scan, depth-8 register prefetch ----------------
// one wave per (b,h); lane: j=lane&31 (value dim), ih=lane>>5 (key half), S[i][j] i in ih*16..+15
__global__ __launch_bounds__(64) void k_scan(const unsigned short* q, const unsigned short* k,
                                             const unsigned short* v, const float* beta,
                                             unsigned short* o){
  int b = blockIdx.x>>2, hh = blockIdx.x&3;
  int lane = threadIdx.x;
  int j = lane&31, ih = lane>>5;
  float S[16];
  #pragma unroll
  for (int m=0;m<16;m++) S[m]=0.f;
  size_t idx0 = ((size_t)b*TT*HH + hh)*dh;     // t-stride 128
  size_t bidx0 = (size_t)b*TT*HH + hh;         // t-stride 4
  const unsigned short* kp = k + idx0 + ih*16;
  const unsigned short* qp = q + idx0 + ih*16;
  const unsigned short* vp = v + idx0 + j;
  const float* bp = beta + bidx0;
  unsigned short* op = o + idx0 + j;

#define DECLS(s) uint4 ka##s, kb##s, qa##s, qb##s; unsigned short vv##s; float bb##s;
  DECLS(0) DECLS(1) DECLS(2) DECLS(3) DECLS(4) DECLS(5) DECLS(6) DECLS(7)

#define LOADS(s, t) { size_t ofs=(size_t)(t)*128; \
  ka##s = *(const uint4*)(kp+ofs); kb##s = *(const uint4*)(kp+ofs+8); \
  qa##s = *(const uint4*)(qp+ofs); qb##s = *(const uint4*)(qp+ofs+8); \
  vv##s = vp[ofs]; bb##s = bp[(size_t)(t)*HH]; }

#define UNPK(dst, A, Bv) \
  dst[0]=blo(A.x); dst[1]=bhi(A.x); dst[2]=blo(A.y); dst[3]=bhi(A.y); \
  dst[4]=blo(A.z); dst[5]=bhi(A.z); dst[6]=blo(A.w); dst[7]=bhi(A.w); \
  dst[8]=blo(Bv.x); dst[9]=bhi(Bv.x); dst[10]=blo(Bv.y); dst[11]=bhi(Bv.y); \
  dst[12]=blo(Bv.z); dst[13]=bhi(Bv.z); dst[14]=blo(Bv.w); dst[15]=bhi(Bv.w);

#define STEPS(s, tt) { \
  float kf[16], qf[16]; \
  UNPK(kf, ka##s, kb##s) \
  UNPK(qf, qa##s, qb##s) \
  float vc=b2f(vv##s), bc=bb##s; \
  float p0=0.f,p1=0.f,p2=0.f,p3=0.f; \
  _Pragma("unroll") \
  for (int m=0;m<4;m++){ p0+=S[m]*kf[m]; p1+=S[m+4]*kf[m+4]; p2+=S[m+8]*kf[m+8]; p3+=S[m+12]*kf[m+12]; } \
  float p=(p0+p1)+(p2+p3); p += __shfl_xor(p,32,64); \
  float err=(vc-p)*bc; \
  float o0=0.f,o1=0.f,o2=0.f,o3=0.f; \
  _Pragma("unroll") \
  for (int m=0;m<4;m++){ \
    S[m]    += kf[m]*err;     o0 += S[m]*qf[m]; \
    S[m+4]  += kf[m+4]*err;   o1 += S[m+4]*qf[m+4]; \
    S[m+8]  += kf[m+8]*err;   o2 += S[m+8]*qf[m+8]; \
    S[m+12] += kf[m+12]*err;  o3 += S[m+12]*qf[m+12]; \
  } \
  float oo=(o0+o1)+(o2+o3); oo += __shfl_xor(oo,32,64); \
  if (ih==0) op[(size_t)(tt)*128] = f2b(oo); }

  LOADS(0,0) LOADS(1,1) LOADS(2,2) LOADS(3,3) LOADS(4,4) LOADS(5,5) LOADS(6,6) LOADS(7,7)
  for (int t=0; t<TT; t+=8){
    STEPS(0,t+0) if (t+8  < TT) LOADS(0, t+8)
    STEPS(1,t+1) if (t+9  < TT) LOADS(1, t+9)
    STEPS(2,t+2) if (t+10 < TT) LOADS(2, t+10)
    STEPS(3,t+3) if (t+11 < TT) LOADS(3, t+11)
    STEPS(4,t+4) if (t+12 < TT) LOADS(4, t+12)
    STEPS(5,t+5) if (t+13 < TT) LOADS(5, t+13)
    STEPS(6,t+6) if (t+14 < TT) LOADS(6, t+14)
    STEPS(7,t+7) if (t+15 < TT) LOADS(7, t+15)
  }
#undef DECLS
#undef LOADS
#undef UNPK
#undef STEPS
}

// ---------------- o = rms(o, hnw)*silu(gate) ----------------
__global__ __launch_bounds__(256) void k_ogate(const unsigned short* __restrict__ o, const unsigned short* __restrict__ gate,
                                               const float* __restrict__ hnwl, unsigned short* __restrict__ tmp){
  int tid=threadIdx.x;
  size_t bt = (size_t)blockIdx.x*2 + (tid>>7);
  int c = tid&127;
  size_t i = bt*DD + c;
  float ov = b2f(o[i]);
  float ss = ov*ov;
  #pragma unroll
  for (int m=1;m<32;m<<=1) ss += __shfl_xor(ss,m,64);
  float r = rsqrtf(ss*(1.0f/32.0f)+1e-5f);
  float g = b2f(gate[i]);
  tmp[i] = f2b(ov*r*hnwl[c&31]*siluf(g));
}

// ---------------- final head: out[M,33] ----------------
__global__ __launch_bounds__(256) void k_head(const unsigned short* __restrict__ hf, const float* __restrict__ hw,
                                              float* __restrict__ out){
  int gid = blockIdx.x*256+threadIdx.x;
  if (gid >= MM*VV) return;
  int row = gid/VV, n = gid - row*VV;
  const unsigned short* a = hf + (size_t)row*DD;
  const float* w = hw + n*DD;
  float s=0.f;
  #pragma unroll
  for (int k2=0;k2<128;k2+=8){
    uint4 av = *(const uint4*)(a+k2);
    float4 wa = *(const float4*)(w+k2);
    float4 wb = *(const float4*)(w+k2+4);
    s += blo(av.x)*wa.x + bhi(av.x)*wa.y + blo(av.y)*wa.z + bhi(av.y)*wa.w;
    s += blo(av.z)*wb.x + bhi(av.z)*wb.y + blo(av.w)*wb.z + bhi(av.w)*wb.w;
  }
  out[gid] = s;
}

extern "C" void kernel_launch(void* const* d_in, const int* in_sizes, int n_in,
                              void* d_out, int out_size, void* d_ws, size_t ws_size,
                              hipStream_t stream){
  const int*   x   = (const int*)d_in[0];
  const float* emb = (const float*)d_in[1];
  const float* qw  = (const float*)d_in[2];
  const float* kw  = (const float*)d_in[3];
  const float* vw  = (const float*)d_in[4];
  const float* qcw = (const float*)d_in[5];
  const float* qcb = (const float*)d_in[6];
  const float* kcw = (const float*)d_in[7];
  const float* kcb = (const float*)d_in[8];
  const float* vcw = (const float*)d_in[9];
  const float* vcb = (const float*)d_in[10];
  const float* ow  = (const float*)d_in[11];
  const float* gw  = (const float*)d_in[12];
  const float* bw  = (const float*)d_in[13];
  const float* hnw = (const float*)d_in[14];
  const float* n1w = (const float*)d_in[15];
  const float* n2w = (const float*)d_in[16];
  const float* m1w = (const float*)d_in[17];
  const float* m2w = (const float*)d_in[18];
  const float* fnw = (const float*)d_in[19];
  const float* hw  = (const float*)d_in[20];

  // ws layout (196.2 MB): h | hn | A | B | C | beta | halo
  char* ws = (char*)d_ws;
  size_t off = 0;
  float* h             = (float*)(ws+off);          off += (size_t)MM*DD*4;
  unsigned short* hn   = (unsigned short*)(ws+off); off += (size_t)MM*DD*2;
  unsigned short* A    = (unsigned short*)(ws+off); off += (size_t)MM*DD*2;
  unsigned short* B    = (unsigned short*)(ws+off); off += (size_t)MM*DD*2;
  unsigned short* C    = (unsigned short*)(ws+off); off += (size_t)MM*DD*2;
  float* beta          = (float*)(ws+off);          off += (size_t)MM*HH*4;
  unsigned short* halo = (unsigned short*)(ws+off); off += (size_t)NCHUNK*9*128*2;
  unsigned short* t1   = A;   // [M,256] spans A+B (both dead at MLP time)

  k_embed<<<MM*DD/256, 256, 0, stream>>>(x, emb, h);
  for (int l=0;l<LL;l++){
    k_rms<<<MM/4,256,0,stream>>>(h, n1w + l*DD, hn);
    k_gemm<0,0><<<dim3(MM/128,2),256,0,stream>>>(hn, qw + l*DD*DD, A, 128, 128);
    k_gemm<0,0><<<dim3(MM/128,2),256,0,stream>>>(hn, kw + l*DD*DD, B, 128, 128);
    k_gemm<0,0><<<dim3(MM/128,2),256,0,stream>>>(hn, vw + l*DD*DD, C, 128, 128);
    k_beta<<<MM/64,256,0,stream>>>(hn, bw + l*HH*DD, beta);
    k_halo<<<NCHUNK*9*128/256,256,0,stream>>>(A, B, C, halo);
    k_conv_ip<<<dim3(NCHUNK,3),256,0,stream>>>(A, B, C,
                                  qcw+l*DD*4, qcb+l*DD, kcw+l*DD*4, kcb+l*DD, vcw+l*DD*4, vcb+l*DD,
                                  halo);
    k_scan<<<BB*HH,64,0,stream>>>(A, B, C, beta, A);          // o overwrites q (in-wave order safe)
    k_gemm<0,0><<<dim3(MM/128,2),256,0,stream>>>(hn, gw + l*DD*DD, C, 128, 128);  // gate -> C
    k_ogate<<<MM/2,256,0,stream>>>(A, C, hnw+l*dh, B);        // tmp -> B
    k_gemm<0,1><<<dim3(MM/128,2),256,0,stream>>>(B, ow + l*DD*DD, h, 128, 128);
    k_rms<<<MM/4,256,0,stream>>>(h, n2w + l*DD, hn);
    k_gemm<1,0><<<dim3(MM/128,4),256,0,stream>>>(hn, m1w + l*2*DD*DD, t1, 256, 128);
    k_gemm<0,1><<<dim3(MM/128,2),256,0,stream>>>(t1, m2w + l*2*DD*DD, h, 128, 256);
  }
  k_rms<<<MM/4,256,0,stream>>>(h, fnw, hn);
  k_head<<<(MM*VV+255)/256,256,0,stream>>>(hn, hw, (float*)d_out);
}

// Round 5
// 4256.651 us; speedup vs baseline: 2.7872x; 2.0098x over previous
//
#include <hip/hip_runtime.h>
#include <hip/hip_bf16.h>
#include <math.h>

#define BB 32
#define TT 4096
#define DD 128
#define HH 4
#define dh 32
#define VV 33
#define LL 4
#define MM (BB*TT)   // 131072 rows
#define NCHUNK (MM/128)  // 1024
#define NC 64        // delta chunks per (b,h): TT/64

typedef short short8 __attribute__((ext_vector_type(8)));
typedef float f32x4 __attribute__((ext_vector_type(4)));

__device__ __forceinline__ float b2f(unsigned short u){
  union{float f; unsigned int x;} v; v.x = ((unsigned int)u)<<16; return v.f;
}
__device__ __forceinline__ unsigned short f2b(float f){
  union{float f; unsigned int x;} v; v.f=f;
  unsigned int r = v.x + 0x7fffu + ((v.x>>16)&1u);
  return (unsigned short)(r>>16);
}
__device__ __forceinline__ float blo(unsigned int u){ union{float f;unsigned int x;}v; v.x=u<<16; return v.f;}
__device__ __forceinline__ float bhi(unsigned int u){ union{float f;unsigned int x;}v; v.x=u&0xffff0000u; return v.f;}
__device__ __forceinline__ float siluf(float x){ return x/(1.0f+expf(-x)); }

// ---------------- embedding ----------------
__global__ __launch_bounds__(256) void k_embed(const int* __restrict__ x, const float* __restrict__ emb,
                                               float* __restrict__ h){
  int i = blockIdx.x*256 + threadIdx.x;
  int bt = i>>7, c = i&127;
  h[i] = emb[x[bt]*DD + c];
}

// ---------------- rms norm ----------------
__global__ __launch_bounds__(256) void k_rms(const float* __restrict__ src, const float* __restrict__ w,
                                             unsigned short* __restrict__ dst){
  int row = blockIdx.x*4 + (threadIdx.x>>6);
  int lane = threadIdx.x&63;
  const float2 xv = *(const float2*)(src + (size_t)row*DD + lane*2);
  float ss = xv.x*xv.x + xv.y*xv.y;
  #pragma unroll
  for (int m=1;m<64;m<<=1) ss += __shfl_xor(ss,m,64);
  float sc = rsqrtf(ss*(1.0f/128.0f)+1e-5f);
  const float2 wv = *(const float2*)(w + lane*2);
  unsigned int o = ((unsigned int)f2b(xv.y*sc*wv.y)<<16) | (unsigned int)f2b(xv.x*sc*wv.x);
  *(unsigned int*)(dst + (size_t)row*DD + lane*2) = o;
}

// ---------------- MFMA GEMM: out[M,N] = A[M,K] @ W[N,K]^T ----------------
template<int ACT, int OUTADD>
__global__ __launch_bounds__(256) void k_gemm(const unsigned short* __restrict__ A,
                                              const float* __restrict__ W,
                                              void* __restrict__ outp, int N, int K){
  __shared__ __align__(16) unsigned short As[128*128];
  __shared__ __align__(16) unsigned short Ws[64*128];
  const int tid = threadIdx.x;
  const int lane = tid & 63, wave = tid >> 6;
  const int row0 = blockIdx.x*128, col0 = blockIdx.y*64;
  const int wr0 = (wave&1)*64, wc0 = (wave>>1)*32;
  const int fr = lane & 15, fq = lane >> 4;
  f32x4 acc[4][2];
  #pragma unroll
  for (int m=0;m<4;m++){
    #pragma unroll
    for (int n=0;n<2;n++) acc[m][n] = (f32x4){0.f,0.f,0.f,0.f};
  }

  for (int kc=0; kc<K; kc+=128){
    #pragma unroll
    for (int ii=0; ii<8; ++ii){
      int flat = tid + ii*256;
      int r = flat>>4, g = flat&15;
      uint4 gv = *(const uint4*)(A + (size_t)(row0+r)*K + kc + g*8);
      *(uint4*)&As[r*128 + ((g^(r&7))<<3)] = gv;
    }
    #pragma unroll
    for (int ii=0; ii<8; ++ii){
      int flat = tid + ii*256;
      int n = flat>>5, q4 = flat&31;
      float4 wv = *(const float4*)(W + (size_t)(col0+n)*K + kc + q4*4);
      uint2 pk;
      pk.x = (unsigned int)f2b(wv.x) | ((unsigned int)f2b(wv.y)<<16);
      pk.y = (unsigned int)f2b(wv.z) | ((unsigned int)f2b(wv.w)<<16);
      int dst = n*128 + ((((q4>>1)^(n&7))<<3) | ((q4&1)<<2));
      *(uint2*)&Ws[dst] = pk;
    }
    __syncthreads();
    #pragma unroll
    for (int ks=0; ks<4; ++ks){
      int gg = ks*4 + fq;
      short8 a[4], b[2];
      #pragma unroll
      for (int m=0;m<4;m++){
        int row = wr0 + m*16 + fr;
        a[m] = *(const short8*)&As[row*128 + ((gg^(row&7))<<3)];
      }
      #pragma unroll
      for (int n=0;n<2;n++){
        int col = wc0 + n*16 + fr;
        b[n] = *(const short8*)&Ws[col*128 + ((gg^(col&7))<<3)];
      }
      #pragma unroll
      for (int m=0;m<4;m++){
        #pragma unroll
        for (int n=0;n<2;n++)
          acc[m][n] = __builtin_amdgcn_mfma_f32_16x16x32_bf16(a[m], b[n], acc[m][n], 0, 0, 0);
      }
    }
    __syncthreads();
  }

  if (OUTADD){
    float* O = (float*)outp;
    #pragma unroll
    for (int m=0;m<4;m++){
      #pragma unroll
      for (int n=0;n<2;n++){
        int ccol = col0 + wc0 + n*16 + fr;
        #pragma unroll
        for (int r=0;r<4;r++){
          int rrow = row0 + wr0 + m*16 + fq*4 + r;
          O[(size_t)rrow*N + ccol] += acc[m][n][r];
        }
      }
    }
  } else {
    unsigned short* O = (unsigned short*)outp;
    #pragma unroll
    for (int m=0;m<4;m++){
      #pragma unroll
      for (int n=0;n<2;n++){
        int ccol = col0 + wc0 + n*16 + fr;
        #pragma unroll
        for (int r=0;r<4;r++){
          int rrow = row0 + wr0 + m*16 + fq*4 + r;
          float vv = acc[m][n][r];
          if (ACT) vv = siluf(vv);
          O[(size_t)rrow*N + ccol] = f2b(vv);
        }
      }
    }
  }
}

// ---------------- beta = sigmoid(hn @ bw^T), N=4 ----------------
__global__ __launch_bounds__(256) void k_beta(const unsigned short* __restrict__ hn,
                                              const float* __restrict__ bwl, float* __restrict__ beta){
  __shared__ unsigned short As[64*128];
  int tid = threadIdx.x; int row0 = blockIdx.x*64;
  #pragma unroll
  for (int ii=0;ii<4;ii++){
    int flat = tid + ii*256;
    int r = flat>>4, v16 = flat&15;
    *(uint4*)&As[r*128 + v16*8] = *(const uint4*)(hn + (size_t)(row0+r)*DD + v16*8);
  }
  __syncthreads();
  int r = tid>>2, n = tid&3;
  const float* wr = bwl + n*DD;
  const unsigned short* ar = &As[r*128];
  float s = 0.f;
  #pragma unroll
  for (int k=0;k<128;k+=8){
    uint4 a = *(const uint4*)(ar + k);
    float4 wa = *(const float4*)(wr + k);
    float4 wb = *(const float4*)(wr + k + 4);
    s += blo(a.x)*wa.x + bhi(a.x)*wa.y + blo(a.y)*wa.z + bhi(a.y)*wa.w;
    s += blo(a.z)*wb.x + bhi(a.z)*wb.y + blo(a.w)*wb.z + bhi(a.w)*wb.w;
  }
  beta[(size_t)(row0+r)*HH + n] = 1.0f/(1.0f+expf(-s));
}

// ---------------- halo save ----------------
__global__ __launch_bounds__(256) void k_halo(const unsigned short* __restrict__ A,
                                              const unsigned short* __restrict__ B,
                                              const unsigned short* __restrict__ C,
                                              unsigned short* __restrict__ halo){
  int i = blockIdx.x*256 + threadIdx.x;
  int ch = i & 127;
  int rt = i >> 7;
  int r3 = rt % 3;
  int tn = (rt/3) % 3;
  int ck = rt / 9;
  unsigned short v = 0;
  if ((ck & 31) != 0){
    const unsigned short* X = (tn==0) ? A : (tn==1) ? B : C;
    v = X[((size_t)ck*128 - 3 + r3)*DD + ch];
  }
  halo[(size_t)i] = v;
}

// ---------------- in-place causal conv(4)+silu(+l2n) ----------------
__global__ __launch_bounds__(256) void k_conv_ip(
    unsigned short* __restrict__ A, unsigned short* __restrict__ B, unsigned short* __restrict__ C,
    const float* __restrict__ qcw, const float* __restrict__ qcb,
    const float* __restrict__ kcw, const float* __restrict__ kcb,
    const float* __restrict__ vcw, const float* __restrict__ vcb,
    const unsigned short* __restrict__ halo){
  __shared__ __align__(16) unsigned short Xs[131*128];
  const int tid = threadIdx.x;
  const int ck = blockIdx.x, tn = blockIdx.y;
  unsigned short* X = (tn==0) ? A : (tn==1) ? B : C;
  const float* w = (tn==0) ? qcw : (tn==1) ? kcw : vcw;
  const float* bi = (tn==0) ? qcb : (tn==1) ? kcb : vcb;

  if (tid < 48){
    int lr = tid>>4, c16 = tid&15;
    *(uint4*)&Xs[lr*128 + c16*8] = *(const uint4*)&halo[((size_t)(ck*3+tn)*3 + lr)*128 + c16*8];
  }
  #pragma unroll
  for (int ii=0; ii<8; ++ii){
    int flat = tid + ii*256;
    int r = flat>>4, c16 = flat&15;
    *(uint4*)&Xs[(3+r)*128 + c16*8] = *(const uint4*)&X[((size_t)ck*128 + r)*DD + c16*8];
  }
  __syncthreads();

  const int rh = tid>>7, c = tid&127;
  float w0=w[c*4+0], w1=w[c*4+1], w2=w[c*4+2], w3=w[c*4+3];
  float bc = bi[c];
  #pragma unroll 2
  for (int rr=0; rr<64; ++rr){
    int row = rr*2 + rh;
    float y = bc + w0*b2f(Xs[(row+0)*128+c]) + w1*b2f(Xs[(row+1)*128+c])
                 + w2*b2f(Xs[(row+2)*128+c]) + w3*b2f(Xs[(row+3)*128+c]);
    y = siluf(y);
    if (tn < 2){
      float s = y*y;
      #pragma unroll
      for (int m=1;m<32;m<<=1) s += __shfl_xor(s,m,64);
      y *= rsqrtf(s + 1e-6f);
      if (tn==0) y *= 0.17677669529663687f;
    }
    X[((size_t)ck*128 + row)*DD + c] = f2b(y);
  }
}

// ======================= chunked delta-rule (WY form) =======================
// chunk C=64, per (b,h): M = I + stril(diag(beta) K K^T)
// W = M^-1 B V, U = M^-1 B K  (phase A, parallel over 8192 chunks)
// E_c = W_c - U_c S ; S += K_c^T E_c  (phase B, serial over 64 chunks, 128 blocks)
// O = Q S_entry + tril(Q K^T, incl diag) E   (phase C, parallel)
// v-layout: elem(b,t,h,d) = (b*TT+t)*128 + h*32 + d

// ---- phase A: one wave per chunk. writes W over v-region, U compact ----
__global__ __launch_bounds__(64) void k_pA(const unsigned short* __restrict__ kbuf,
                                           unsigned short* vwbuf,
                                           const float* __restrict__ betab,
                                           unsigned short* __restrict__ Ubuf){
  __shared__ float Ab[64][65];
  __shared__ float WU[64][72];
  __shared__ float bs[64];
  const int c = blockIdx.x, bh = blockIdx.y;
  const int b = bh>>2, h = bh&3;
  const int lane = threadIdx.x;
  const int fr = lane&15, fg = lane>>4;
  const size_t base = ((size_t)b*TT + c*64)*128 + h*32;
  const size_t bbase = ((size_t)b*TT + c*64)*4 + h;

  bs[lane] = betab[bbase + (size_t)lane*4];

  short8 kf[4];
  #pragma unroll
  for (int mt=0;mt<4;mt++)
    kf[mt] = *(const short8*)(kbuf + base + (size_t)(mt*16+fr)*128 + fg*8);

  // Ab[t][s] = beta_t * (k_t . k_s), lower tiles only
  #pragma unroll
  for (int mt=0;mt<4;mt++){
    #pragma unroll
    for (int nt=0;nt<4;nt++){
      if (nt>mt) continue;
      f32x4 a = (f32x4){0.f,0.f,0.f,0.f};
      a = __builtin_amdgcn_mfma_f32_16x16x32_bf16(kf[mt], kf[nt], a, 0,0,0);
      #pragma unroll
      for (int r=0;r<4;r++){
        int t = mt*16 + fg*4 + r;
        Ab[t][nt*16+fr] = a[r]*bs[t];
      }
    }
  }

  // forward substitution: lane<32 -> W col lane, lane>=32 -> U col lane-32
  const unsigned short* xp = ((lane<32)? (const unsigned short*)vwbuf : kbuf) + base + (lane&31);
  unsigned short xnext = xp[0];
  const size_t ub = ((size_t)bh*NC + c)*2048;
  for (int t=0;t<64;t++){
    float acc = b2f(xnext)*bs[t];
    if (t<63) xnext = xp[(size_t)(t+1)*128];
    for (int s=0;s<t;s++) acc -= Ab[t][s]*WU[s][lane];
    WU[t][lane] = acc;
    float nb = __shfl_down(acc, 1, 64);
    if ((lane&1)==0){
      unsigned int pk = (unsigned int)f2b(acc) | ((unsigned int)f2b(nb)<<16);
      if (lane<32) *(unsigned int*)(vwbuf + base + (size_t)t*128 + lane) = pk;
      else         *(unsigned int*)(Ubuf + ub + t*32 + (lane-32)) = pk;
    }
  }
}

// ---- phase B: one wave per (b,h), serial over 64 chunks ----
__global__ __launch_bounds__(64) void k_pB(const unsigned short* __restrict__ kbuf,
                                           unsigned short* webuf,
                                           const unsigned short* __restrict__ Ubuf,
                                           unsigned short* __restrict__ Sent){
  __shared__ float Sl[32][33];
  __shared__ unsigned short El[64][40];
  __shared__ unsigned short Kl[64][40];
  const int bh = blockIdx.x, b = bh>>2, h = bh&3;
  const int lane = threadIdx.x, fr = lane&15, fg = lane>>4;
  for (int i=lane; i<32*33; i+=64) ((float*)Sl)[i] = 0.f;
  f32x4 sc[2][2];
  #pragma unroll
  for (int it=0;it<2;it++){
    #pragma unroll
    for (int ct=0;ct<2;ct++) sc[it][ct]=(f32x4){0.f,0.f,0.f,0.f};
  }

  for (int c=0;c<NC;c++){
    const size_t base = ((size_t)b*TT + c*64)*128 + h*32;
    const size_t ub = ((size_t)bh*NC + c)*2048;
    // stage K row(lane) and W row(lane) into LDS (W into El, overwritten by E later)
    {
      const unsigned short* kr = kbuf + base + (size_t)lane*128;
      const unsigned short* wr = webuf + base + (size_t)lane*128;
      uint4 a0=*(const uint4*)(kr),   a1=*(const uint4*)(kr+8);
      uint4 a2=*(const uint4*)(kr+16),a3=*(const uint4*)(kr+24);
      uint4 b0=*(const uint4*)(wr),   b1=*(const uint4*)(wr+8);
      uint4 b2=*(const uint4*)(wr+16),b3=*(const uint4*)(wr+24);
      *(uint4*)&Kl[lane][0]=a0; *(uint4*)&Kl[lane][8]=a1;
      *(uint4*)&Kl[lane][16]=a2; *(uint4*)&Kl[lane][24]=a3;
      *(uint4*)&El[lane][0]=b0; *(uint4*)&El[lane][8]=b1;
      *(uint4*)&El[lane][16]=b2; *(uint4*)&El[lane][24]=b3;
    }
    // U A-frags
    short8 uf[4];
    #pragma unroll
    for (int mt=0;mt<4;mt++)
      uf[mt] = *(const short8*)(Ubuf + ub + (size_t)(mt*16+fr)*32 + fg*8);
    // acc init = W (C/D layout) from El
    f32x4 acc[4][2];
    #pragma unroll
    for (int mt=0;mt<4;mt++){
      #pragma unroll
      for (int ct=0;ct<2;ct++){
        #pragma unroll
        for (int r=0;r<4;r++)
          acc[mt][ct][r] = b2f(El[mt*16+fg*4+r][ct*16+fr]);
      }
    }
    // S B-frags (negated) + S_entry store (positive)
    short8 sb[2];
    #pragma unroll
    for (int ct=0;ct<2;ct++){
      short8 neg, pos;
      #pragma unroll
      for (int jj=0;jj<8;jj++){
        float sv = Sl[fg*8+jj][ct*16+fr];
        pos[jj]=(short)f2b(sv); neg[jj]=(short)f2b(-sv);
      }
      sb[ct]=neg;
      *(short8*)(Sent + ((size_t)bh*NC + c)*1024 + ct*512 + lane*8) = pos;
    }
    // E = W + U*(-S)
    #pragma unroll
    for (int mt=0;mt<4;mt++){
      #pragma unroll
      for (int ct=0;ct<2;ct++)
        acc[mt][ct] = __builtin_amdgcn_mfma_f32_16x16x32_bf16(uf[mt], sb[ct], acc[mt][ct],0,0,0);
    }
    // write E to LDS (over W) and global (over W)
    #pragma unroll
    for (int mt=0;mt<4;mt++){
      #pragma unroll
      for (int ct=0;ct<2;ct++){
        #pragma unroll
        for (int r=0;r<4;r++){
          unsigned short ev = f2b(acc[mt][ct][r]);
          int t = mt*16+fg*4+r, j = ct*16+fr;
          El[t][j] = ev;
          webuf[base + (size_t)t*128 + j] = ev;
        }
      }
    }
    // K^T A-frags, E B-frags
    short8 ka[2][2], eb[2][2];
    #pragma unroll
    for (int it=0;it<2;it++){
      #pragma unroll
      for (int ks=0;ks<2;ks++){
        short8 tmp;
        #pragma unroll
        for (int jj=0;jj<8;jj++) tmp[jj] = (short)Kl[ks*32+fg*8+jj][it*16+fr];
        ka[it][ks]=tmp;
      }
    }
    #pragma unroll
    for (int ct=0;ct<2;ct++){
      #pragma unroll
      for (int ks=0;ks<2;ks++){
        short8 tmp;
        #pragma unroll
        for (int jj=0;jj<8;jj++) tmp[jj] = (short)El[ks*32+fg*8+jj][ct*16+fr];
        eb[ct][ks]=tmp;
      }
    }
    #pragma unroll
    for (int it=0;it<2;it++){
      #pragma unroll
      for (int ct=0;ct<2;ct++){
        #pragma unroll
        for (int ks=0;ks<2;ks++)
          sc[it][ct] = __builtin_amdgcn_mfma_f32_16x16x32_bf16(ka[it][ks], eb[ct][ks], sc[it][ct],0,0,0);
      }
    }
    // master S (f32, exact) back to Sl for next chunk's B-frags
    #pragma unroll
    for (int it=0;it<2;it++){
      #pragma unroll
      for (int ct=0;ct<2;ct++){
        #pragma unroll
        for (int r=0;r<4;r++)
          Sl[it*16+fg*4+r][ct*16+fr] = sc[it][ct][r];
      }
    }
  }
}

// ---- phase C: one wave per chunk. O = Q S_entry + tril(QK^T) E ----
__global__ __launch_bounds__(64) void k_pC(unsigned short* qobuf,
                                           const unsigned short* __restrict__ kbuf,
                                           const unsigned short* __restrict__ ebuf,
                                           const unsigned short* __restrict__ Sent){
  __shared__ unsigned short Pl[64][72];
  __shared__ unsigned short El[64][40];
  const int c = blockIdx.x, bh = blockIdx.y, b=bh>>2, h=bh&3;
  const int lane=threadIdx.x, fr=lane&15, fg=lane>>4;
  const size_t base = ((size_t)b*TT + c*64)*128 + h*32;
  // zero Pl
  #pragma unroll
  for (int i=0;i<9;i++) *(uint4*)&Pl[lane][i*8] = (uint4){0u,0u,0u,0u};
  // stage E
  {
    const unsigned short* er = ebuf + base + (size_t)lane*128;
    uint4 a0=*(const uint4*)(er),   a1=*(const uint4*)(er+8);
    uint4 a2=*(const uint4*)(er+16),a3=*(const uint4*)(er+24);
    *(uint4*)&El[lane][0]=a0; *(uint4*)&El[lane][8]=a1;
    *(uint4*)&El[lane][16]=a2; *(uint4*)&El[lane][24]=a3;
  }
  short8 qf[4], kf[4];
  #pragma unroll
  for (int mt=0;mt<4;mt++){
    qf[mt] = *(const short8*)(qobuf + base + (size_t)(mt*16+fr)*128 + fg*8);
    kf[mt] = *(const short8*)(kbuf  + base + (size_t)(mt*16+fr)*128 + fg*8);
  }
  // P = tril(QK^T) -> Pl (bf16)
  #pragma unroll
  for (int mt=0;mt<4;mt++){
    #pragma unroll
    for (int nt=0;nt<4;nt++){
      if (nt>mt) continue;
      f32x4 p = (f32x4){0.f,0.f,0.f,0.f};
      p = __builtin_amdgcn_mfma_f32_16x16x32_bf16(qf[mt], kf[nt], p,0,0,0);
      #pragma unroll
      for (int r=0;r<4;r++){
        int t = mt*16+fg*4+r, s = nt*16+fr;
        Pl[t][s] = (s<=t)? f2b(p[r]) : (unsigned short)0;
      }
    }
  }
  // O = Q*Sent
  f32x4 acc[4][2];
  short8 sf[2];
  #pragma unroll
  for (int ct=0;ct<2;ct++)
    sf[ct] = *(const short8*)(Sent + ((size_t)bh*NC + c)*1024 + ct*512 + lane*8);
  #pragma unroll
  for (int mt=0;mt<4;mt++){
    #pragma unroll
    for (int ct=0;ct<2;ct++){
      acc[mt][ct]=(f32x4){0.f,0.f,0.f,0.f};
      acc[mt][ct]=__builtin_amdgcn_mfma_f32_16x16x32_bf16(qf[mt], sf[ct], acc[mt][ct],0,0,0);
    }
  }
  // O += P*E
  short8 ebf[2][2];
  #pragma unroll
  for (int ct=0;ct<2;ct++){
    #pragma unroll
    for (int ks=0;ks<2;ks++){
      short8 tmp;
      #pragma unroll
      for (int jj=0;jj<8;jj++) tmp[jj]=(short)El[ks*32+fg*8+jj][ct*16+fr];
      ebf[ct][ks]=tmp;
    }
  }
  #pragma unroll
  for (int mt=0;mt<4;mt++){
    #pragma unroll
    for (int ks=0;ks<2;ks++){
      short8 pa = *(const short8*)&Pl[mt*16+fr][ks*32+fg*8];
      #pragma unroll
      for (int ct=0;ct<2;ct++)
        acc[mt][ct]=__builtin_amdgcn_mfma_f32_16x16x32_bf16(pa, ebf[ct][ks], acc[mt][ct],0,0,0);
    }
  }
  // store O over Q
  #pragma unroll
  for (int mt=0;mt<4;mt++){
    #pragma unroll
    for (int ct=0;ct<2;ct++){
      #pragma unroll
      for (int r=0;r<4;r++)
        qobuf[base + (size_t)(mt*16+fg*4+r)*128 + ct*16+fr] = f2b(acc[mt][ct][r]);
    }
  }
}

// ---------------- fallback sequential scan (round-2 version) ----------------
__global__ __launch_bounds__(64) void k_scan(const unsigned short* q, const unsigned short* k,
                                             const unsigned short* v, const float* beta,
                                             unsigned short* o){
  int b = blockIdx.x>>2, hh = blockIdx.x&3;
  int lane = threadIdx.x;
  int j = lane&31, ih = lane>>5;
  float S[16];
  #pragma unroll
  for (int m=0;m<16;m++) S[m]=0.f;
  size_t idx0 = ((size_t)b*TT*HH + hh)*dh;
  size_t bidx0 = (size_t)b*TT*HH + hh;
  const unsigned short* kp = k + idx0 + ih*16;
  const unsigned short* qp = q + idx0 + ih*16;
  for (int t=0;t<TT;t++){
    size_t ofs=(size_t)t*128;
    uint4 ka=*(const uint4*)(kp+ofs), kb=*(const uint4*)(kp+ofs+8);
    uint4 qa=*(const uint4*)(qp+ofs), qb=*(const uint4*)(qp+ofs+8);
    float kf[16], qf[16];
    kf[0]=blo(ka.x);kf[1]=bhi(ka.x);kf[2]=blo(ka.y);kf[3]=bhi(ka.y);
    kf[4]=blo(ka.z);kf[5]=bhi(ka.z);kf[6]=blo(ka.w);kf[7]=bhi(ka.w);
    kf[8]=blo(kb.x);kf[9]=bhi(kb.x);kf[10]=blo(kb.y);kf[11]=bhi(kb.y);
    kf[12]=blo(kb.z);kf[13]=bhi(kb.z);kf[14]=blo(kb.w);kf[15]=bhi(kb.w);
    qf[0]=blo(qa.x);qf[1]=bhi(qa.x);qf[2]=blo(qa.y);qf[3]=bhi(qa.y);
    qf[4]=blo(qa.z);qf[5]=bhi(qa.z);qf[6]=blo(qa.w);qf[7]=bhi(qa.w);
    qf[8]=blo(qb.x);qf[9]=bhi(qb.x);qf[10]=blo(qb.y);qf[11]=bhi(qb.y);
    qf[12]=blo(qb.z);qf[13]=bhi(qb.z);qf[14]=blo(qb.w);qf[15]=bhi(qb.w);
    float vc = b2f(v[idx0+ofs+j]), bc = beta[bidx0+(size_t)t*4];
    float p0=0,p1=0,p2=0,p3=0;
    #pragma unroll
    for (int m=0;m<4;m++){
      p0 += S[m]*kf[m]; p1 += S[m+4]*kf[m+4]; p2 += S[m+8]*kf[m+8]; p3 += S[m+12]*kf[m+12];
    }
    float p = (p0+p1)+(p2+p3);
    p += __shfl_xor(p, 32, 64);
    float err = (vc - p)*bc;
    float o0=0,o1=0,o2=0,o3=0;
    #pragma unroll
    for (int m=0;m<4;m++){
      S[m]    += kf[m]*err;     o0 += S[m]*qf[m];
      S[m+4]  += kf[m+4]*err;   o1 += S[m+4]*qf[m+4];
      S[m+8]  += kf[m+8]*err;   o2 += S[m+8]*qf[m+8];
      S[m+12] += kf[m+12]*err;  o3 += S[m+12]*qf[m+12];
    }
    float oo = (o0+o1)+(o2+o3);
    oo += __shfl_xor(oo, 32, 64);
    if (ih==0) o[idx0 + ofs + j] = f2b(oo);
  }
}

// ---------------- o = rms(o, hnw)*silu(gate) ----------------
__global__ __launch_bounds__(256) void k_ogate(const unsigned short* __restrict__ o, const unsigned short* __restrict__ gate,
                                               const float* __restrict__ hnwl, unsigned short* __restrict__ tmp){
  int tid=threadIdx.x;
  size_t bt = (size_t)blockIdx.x*2 + (tid>>7);
  int c = tid&127;
  size_t i = bt*DD + c;
  float ov = b2f(o[i]);
  float ss = ov*ov;
  #pragma unroll
  for (int m=1;m<32;m<<=1) ss += __shfl_xor(ss,m,64);
  float r = rsqrtf(ss*(1.0f/32.0f)+1e-5f);
  float g = b2f(gate[i]);
  tmp[i] = f2b(ov*r*hnwl[c&31]*siluf(g));
}

// ---------------- final head ----------------
__global__ __launch_bounds__(256) void k_head(const unsigned short* __restrict__ hf, const float* __restrict__ hw,
                                              float* __restrict__ out){
  int gid = blockIdx.x*256+threadIdx.x;
  if (gid >= MM*VV) return;
  int row = gid/VV, n = gid - row*VV;
  const unsigned short* a = hf + (size_t)row*DD;
  const float* w = hw + n*DD;
  float s=0.f;
  #pragma unroll
  for (int k2=0;k2<128;k2+=8){
    uint4 av = *(const uint4*)(a+k2);
    float4 wa = *(const float4*)(w+k2);
    float4 wb = *(const float4*)(w+k2+4);
    s += blo(av.x)*wa.x + bhi(av.x)*wa.y + blo(av.y)*wa.z + bhi(av.y)*wa.w;
    s += blo(av.z)*wb.x + bhi(av.z)*wb.y + blo(av.w)*wb.z + bhi(av.w)*wb.w;
  }
  out[gid] = s;
}

extern "C" void kernel_launch(void* const* d_in, const int* in_sizes, int n_in,
                              void* d_out, int out_size, void* d_ws, size_t ws_size,
                              hipStream_t stream){
  const int*   x   = (const int*)d_in[0];
  const float* emb = (const float*)d_in[1];
  const float* qw  = (const float*)d_in[2];
  const float* kw  = (const float*)d_in[3];
  const float* vw  = (const float*)d_in[4];
  const float* qcw = (const float*)d_in[5];
  const float* qcb = (const float*)d_in[6];
  const float* kcw = (const float*)d_in[7];
  const float* kcb = (const float*)d_in[8];
  const float* vcw = (const float*)d_in[9];
  const float* vcb = (const float*)d_in[10];
  const float* ow  = (const float*)d_in[11];
  const float* gw  = (const float*)d_in[12];
  const float* bw  = (const float*)d_in[13];
  const float* hnw = (const float*)d_in[14];
  const float* n1w = (const float*)d_in[15];
  const float* n2w = (const float*)d_in[16];
  const float* m1w = (const float*)d_in[17];
  const float* m2w = (const float*)d_in[18];
  const float* fnw = (const float*)d_in[19];
  const float* hw  = (const float*)d_in[20];

  // ws layout: h | hn | A | B | C | beta | halo | U | Sent
  char* ws = (char*)d_ws;
  size_t off = 0;
  float* h             = (float*)(ws+off);          off += (size_t)MM*DD*4;
  unsigned short* hn   = (unsigned short*)(ws+off); off += (size_t)MM*DD*2;
  unsigned short* A    = (unsigned short*)(ws+off); off += (size_t)MM*DD*2;
  unsigned short* B    = (unsigned short*)(ws+off); off += (size_t)MM*DD*2;
  unsigned short* C    = (unsigned short*)(ws+off); off += (size_t)MM*DD*2;
  float* beta          = (float*)(ws+off);          off += (size_t)MM*HH*4;
  unsigned short* halo = (unsigned short*)(ws+off); off += (size_t)NCHUNK*9*128*2;
  unsigned short* U    = (unsigned short*)(ws+off); off += (size_t)MM*DD*2;      // 8192 chunks * 2048
  unsigned short* Sent = (unsigned short*)(ws+off); off += (size_t)128*NC*1024*2;
  const size_t NEED = off;
  unsigned short* t1   = A;
  const bool chunked = (ws_size >= NEED);

  k_embed<<<MM*DD/256, 256, 0, stream>>>(x, emb, h);
  for (int l=0;l<LL;l++){
    k_rms<<<MM/4,256,0,stream>>>(h, n1w + l*DD, hn);
    k_gemm<0,0><<<dim3(MM/128,2),256,0,stream>>>(hn, qw + l*DD*DD, A, 128, 128);
    k_gemm<0,0><<<dim3(MM/128,2),256,0,stream>>>(hn, kw + l*DD*DD, B, 128, 128);
    k_gemm<0,0><<<dim3(MM/128,2),256,0,stream>>>(hn, vw + l*DD*DD, C, 128, 128);
    k_beta<<<MM/64,256,0,stream>>>(hn, bw + l*HH*DD, beta);
    k_halo<<<NCHUNK*9*128/256,256,0,stream>>>(A, B, C, halo);
    k_conv_ip<<<dim3(NCHUNK,3),256,0,stream>>>(A, B, C,
                                  qcw+l*DD*4, qcb+l*DD, kcw+l*DD*4, kcb+l*DD, vcw+l*DD*4, vcb+l*DD,
                                  halo);
    if (chunked){
      k_pA<<<dim3(NC, BB*HH), 64, 0, stream>>>(B, C, beta, U);
      k_pB<<<BB*HH, 64, 0, stream>>>(B, C, U, Sent);
      k_pC<<<dim3(NC, BB*HH), 64, 0, stream>>>(A, B, C, Sent);
    } else {
      k_scan<<<BB*HH,64,0,stream>>>(A, B, C, beta, A);
    }
    k_gemm<0,0><<<dim3(MM/128,2),256,0,stream>>>(hn, gw + l*DD*DD, C, 128, 128);
    k_ogate<<<MM/2,256,0,stream>>>(A, C, hnw+l*dh, B);
    k_gemm<0,1><<<dim3(MM/128,2),256,0,stream>>>(B, ow + l*DD*DD, h, 128, 128);
    k_rms<<<MM/4,256,0,stream>>>(h, n2w + l*DD, hn);
    k_gemm<1,0><<<dim3(MM/128,4),256,0,stream>>>(hn, m1w + l*2*DD*DD, t1, 256, 128);
    k_gemm<0,1><<<dim3(MM/128,2),256,0,stream>>>(t1, m2w + l*2*DD*DD, h, 128, 256);
  }
  k_rms<<<MM/4,256,0,stream>>>(h, fnw, hn);
  k_head<<<(MM*VV+255)/256,256,0,stream>>>(hn, hw, (float*)d_out);
}